// Round 1
// baseline (357.404 us; speedup 1.0000x reference)
//
#include <hip/hip_runtime.h>

#define B_   2
#define N_   32768
#define M_   4096
#define C_   128
#define OUT_ 128
#define IN_  131

#define NSPLIT 16
#define MCHUNK (M_ / NSPLIT)     // 256 points per split
#define NQ     (B_ * N_)         // 65536 total queries

// ---------------------------------------------------------------------------
// K1: split brute-force 3-NN, branchless top-3, explicit scalar state.
// (byte-identical — control; VALU-issue-bound at exactness-required op count)
// ---------------------------------------------------------------------------
#define NN_DECL(X)                                                        \
    float x0##X, x1##X, x2##X, xx##X;                                     \
    float bd0##X = 1e30f, bd1##X = 1e30f, bd2##X = 1e30f;                 \
    int   bi0##X = 0,     bi1##X = 0,     bi2##X = 0;

#define NN_LOAD(X, QQ) {                                                  \
    const int qi = q0 + (QQ) * 256 + t;                                   \
    x0##X = x[(size_t)qi*3+0];                                            \
    x1##X = x[(size_t)qi*3+1];                                            \
    x2##X = x[(size_t)qi*3+2];                                            \
    xx##X = __fadd_rn(__fadd_rn(__fmul_rn(x0##X,x0##X),                   \
                                __fmul_rn(x1##X,x1##X)),                  \
                      __fmul_rn(x2##X,x2##X)); }

#define NN_STEP(X) {                                                      \
    float dot = __fadd_rn(__fadd_rn(__fmul_rn(x0##X,s.x),                 \
                                    __fmul_rn(x1##X,s.y)),                \
                          __fmul_rn(x2##X,s.z));                          \
    float d2 = __fadd_rn(__fmaf_rn(-2.0f, dot, xx##X), s.w);              \
    const float k0 = bd0##X, k1 = bd1##X, k2 = bd2##X;                    \
    const bool c0 = d2 < k0, c1 = d2 < k1, c2 = d2 < k2;                  \
    bi2##X = c1 ? bi1##X : (c2 ? m : bi2##X);                             \
    bi1##X = c0 ? bi0##X : (c1 ? m : bi1##X);                             \
    bi0##X = c0 ? m : bi0##X;                                             \
    bd0##X = fminf(k0, d2);                                               \
    bd1##X = __builtin_amdgcn_fmed3f(d2, k0, k1);                         \
    bd2##X = __builtin_amdgcn_fmed3f(d2, k1, k2); }

#define NN_STORE(X, QQ) {                                                 \
    const int qi = q0 + (QQ) * 256 + t;                                   \
    part_d[(size_t)split * NQ + qi] =                                     \
        make_float4(bd0##X, bd1##X, bd2##X, 0.f);                         \
    part_i[(size_t)split * NQ + qi] =                                     \
        make_int4(bi0##X, bi1##X, bi2##X, 0); }

__global__ __launch_bounds__(256, 4) void nn_split_kernel(const float* __restrict__ x,
                                                          const float* __restrict__ sx,
                                                          float4* __restrict__ part_d,
                                                          int4* __restrict__ part_i) {
    __shared__ float4 spts[MCHUNK];   // 4 KB
    const int split = blockIdx.x & (NSPLIT - 1);
    const int qb    = blockIdx.x >> 4;
    const int q0    = qb * 1024;
    const int b     = q0 >> 15;                     // N_=32768
    const int t     = threadIdx.x;

    // stage + pack this split's points (|s|^2 in reference rounding order)
    {
        const float* sp = sx + ((size_t)b * M_ + split * MCHUNK + t) * 3;
        float s0 = sp[0], s1 = sp[1], s2 = sp[2];
        float ss = __fadd_rn(__fadd_rn(__fmul_rn(s0,s0), __fmul_rn(s1,s1)),
                             __fmul_rn(s2,s2));
        spts[t] = make_float4(s0, s1, s2, ss);
    }
    __syncthreads();

    NN_DECL(A) NN_DECL(B) NN_DECL(C) NN_DECL(D)
    NN_LOAD(A, 0) NN_LOAD(B, 1) NN_LOAD(C, 2) NN_LOAD(D, 3)

    const int m_base = split * MCHUNK;
    #pragma unroll 2
    for (int j = 0; j < MCHUNK; ++j) {
        const float4 s = spts[j];
        const int m = m_base + j;
        NN_STEP(A) NN_STEP(B) NN_STEP(C) NN_STEP(D)
    }

    NN_STORE(A, 0) NN_STORE(B, 1) NN_STORE(C, 2) NN_STORE(D, 3)
}

// ---------------------------------------------------------------------------
// K2a: G = features @ W1f^T over all B*M sampled points (8192 rows, K=128).
// (unchanged)
// ---------------------------------------------------------------------------
__global__ __launch_bounds__(256) void pre_gemm_kernel(const float* __restrict__ features,
                                                       const float* __restrict__ w1,
                                                       float* __restrict__ G) {
    __shared__ float sI[16][132];
    __shared__ float sW[16][132];
    const int row0 = blockIdx.x * 128;
    const int tid  = threadIdx.x;
    const int tr   = tid & 15;
    const int tc   = tid >> 4;
    float acc[8][8] = {};

    for (int kc = 0; kc < 8; ++kc) {
        #pragma unroll
        for (int j = 0; j < 2; ++j) {
            int id  = j * 256 + tid;
            int row = id >> 2, kq = id & 3;
            float4 g = ((const float4*)features)[(size_t)(row0 + row) * 32 + kc * 4 + kq];
            sI[kq*4+0][row] = g.x; sI[kq*4+1][row] = g.y;
            sI[kq*4+2][row] = g.z; sI[kq*4+3][row] = g.w;
        }
        {
            int o = tid >> 1, kk0 = (tid & 1) * 8;
            #pragma unroll
            for (int kk = 0; kk < 8; ++kk)
                sW[kk0+kk][o] = w1[(size_t)o * IN_ + 3 + kc*16 + kk0 + kk];
        }
        __syncthreads();
        #pragma unroll
        for (int kk = 0; kk < 16; ++kk) {
            float4 a0 = *(const float4*)&sI[kk][tr*8];
            float4 a1 = *(const float4*)&sI[kk][tr*8+4];
            float4 c0 = *(const float4*)&sW[kk][tc*8];
            float4 c1 = *(const float4*)&sW[kk][tc*8+4];
            float av[8] = {a0.x,a0.y,a0.z,a0.w,a1.x,a1.y,a1.z,a1.w};
            float bv[8] = {c0.x,c0.y,c0.z,c0.w,c1.x,c1.y,c1.z,c1.w};
            #pragma unroll
            for (int i = 0; i < 8; ++i)
                #pragma unroll
                for (int j = 0; j < 8; ++j)
                    acc[i][j] = fmaf(av[i], bv[j], acc[i][j]);
        }
        __syncthreads();
    }

    #pragma unroll
    for (int i = 0; i < 8; ++i) {
        int r = row0 + tr*8 + i;
        float4 o0 = make_float4(acc[i][0], acc[i][1], acc[i][2], acc[i][3]);
        float4 o1 = make_float4(acc[i][4], acc[i][5], acc[i][6], acc[i][7]);
        ((float4*)G)[(size_t)r * 32 + tc*2 + 0] = o0;
        ((float4*)G)[(size_t)r * 32 + tc*2 + 1] = o1;
    }
}

// ---------------------------------------------------------------------------
// K3 (fused tail, SOFTWARE-PIPELINED):
//   - sA/sW double-buffered (2 x [16][132] each, LDS 23->39 KB; still
//     2 blocks/CU which the 512-block grid caps anyway).
//   - Gathers + w2 loads for chunk kc+1 are issued into REGISTERS before
//     the FMA core of chunk kc -> ~2000 cycles of FMA issue hides the
//     L2 gather latency that was previously fully exposed.
//   - One barrier per chunk instead of two: per-thread order
//     {FMA-read(cur); build-write(nxt); barrier} satisfies RAW on nxt
//     (write@k -> barrier@k -> read@k+1) and WAR on cur
//     (read@k -> barrier@k -> write@k+1).
//   - sIdx/sX re-reads hoisted out of the kc loop (constant after phase 0).
//   All H/FMA/epilogue arithmetic expressions are character-identical to
//   the proven version (same rounding).
// ---------------------------------------------------------------------------
__global__ __launch_bounds__(256) void fused_tail_kernel(const float4* __restrict__ part_d,
                                                         const int4* __restrict__ part_i,
                                                         const float* __restrict__ G,
                                                         const float* __restrict__ x,
                                                         const float* __restrict__ w1,
                                                         const float* __restrict__ b1,
                                                         const float* __restrict__ w2,
                                                         const float* __restrict__ b2,
                                                         float* __restrict__ out) {
    __shared__ float  sA[2][16][132];   // H chunk [buf][k][row]     16.5 KB
    __shared__ float  sW[2][16][132];   // w2 chunk [buf][k][out]    16.5 KB
    __shared__ int4   sIdx[128];        // merged top-3 per query
    __shared__ float4 sX[128];          // query coords
    __shared__ float4 sWX[128];         // (wx0,wx1,wx2,b1) per channel
    const int row0 = blockIdx.x * 128;
    const int tid  = threadIdx.x;
    const int tr   = tid & 15;
    const int tc   = tid >> 4;
    const int b    = row0 >> 15;

    // ---- Phase 0: merge (threads 0-127) || stage w1-xyz table (128-255) ----
    if (tid < 128) {
        const int q = row0 + tid;
        float b0 = 1e30f, b1v = 1e30f, b2v = 1e30f;
        int   i0 = 0,     i1 = 0,      i2 = 0;
        #pragma unroll
        for (int s = 0; s < NSPLIT; ++s) {
            float4 d = part_d[(size_t)s * NQ + q];
            int4   i = part_i[(size_t)s * NQ + q];
            if (d.x < b2v) { if (d.x < b1v) { b2v=b1v; i2=i1;
                if (d.x < b0) { b1v=b0; i1=i0; b0=d.x; i0=i.x; }
                else          { b1v=d.x; i1=i.x; } } else { b2v=d.x; i2=i.x; } }
            if (d.y < b2v) { if (d.y < b1v) { b2v=b1v; i2=i1;
                if (d.y < b0) { b1v=b0; i1=i0; b0=d.y; i0=i.y; }
                else          { b1v=d.y; i1=i.y; } } else { b2v=d.y; i2=i.y; } }
            if (d.z < b2v) { if (d.z < b1v) { b2v=b1v; i2=i1;
                if (d.z < b0) { b1v=b0; i1=i0; b0=d.z; i0=i.z; }
                else          { b1v=d.z; i1=i.z; } } else { b2v=d.z; i2=i.z; } }
        }
        sIdx[tid] = make_int4(i0, i1, i2, 0);
        const float* xp = x + (size_t)q * 3;
        sX[tid] = make_float4(xp[0], xp[1], xp[2], 0.f);
    } else {
        const int c = tid - 128;
        sWX[c] = make_float4(w1[(size_t)c*IN_+0], w1[(size_t)c*IN_+1],
                             w1[(size_t)c*IN_+2], b1[c]);
    }
    __syncthreads();

    // ---- hoisted per-thread constants (sIdx/sX fixed after phase 0) ----
    const float4* gb   = (const float4*)G + (size_t)b * M_ * 32;
    const float4* w2v4 = (const float4*)w2;
    const int r0 = tid >> 2;        // j=0 row
    const int r1 = 64 + r0;         // j=1 row
    const int kq = tid & 3;
    const int4   v0  = sIdx[r0], v1  = sIdx[r1];
    const float4 xr0 = sX[r0],   xr1 = sX[r1];

    float acc[8][8] = {};
    float4 pa0, pe0, pf0, pw0, pa1, pe1, pf1, pw1;

#define TLOAD(KC) {                                                       \
    const int c4 = (KC)*4 + kq;                                           \
    pa0 = gb[(size_t)v0.x*32 + c4];                                       \
    pe0 = gb[(size_t)v0.y*32 + c4];                                       \
    pf0 = gb[(size_t)v0.z*32 + c4];                                       \
    pa1 = gb[(size_t)v1.x*32 + c4];                                       \
    pe1 = gb[(size_t)v1.y*32 + c4];                                       \
    pf1 = gb[(size_t)v1.z*32 + c4];                                       \
    pw0 = w2v4[(size_t)r0*32 + c4];                                       \
    pw1 = w2v4[(size_t)r1*32 + c4]; }

#define TBUILD(BUF, KC) {                                                 \
    const int c4 = (KC)*4 + kq;                                           \
    const float4 q0 = sWX[c4*4+0], q1 = sWX[c4*4+1];                      \
    const float4 q2 = sWX[c4*4+2], q3 = sWX[c4*4+3];                      \
    float h;                                                              \
    h = ((pa0.x + pe0.x) + pf0.x) * (1.0f/3.0f);                          \
    h = fmaf(q0.x,xr0.x, fmaf(q0.y,xr0.y, fmaf(q0.z,xr0.z, h))) + q0.w;   \
    sA[BUF][kq*4+0][r0] = h > 0.0f ? h : 0.0f;                            \
    h = ((pa0.y + pe0.y) + pf0.y) * (1.0f/3.0f);                          \
    h = fmaf(q1.x,xr0.x, fmaf(q1.y,xr0.y, fmaf(q1.z,xr0.z, h))) + q1.w;   \
    sA[BUF][kq*4+1][r0] = h > 0.0f ? h : 0.0f;                            \
    h = ((pa0.z + pe0.z) + pf0.z) * (1.0f/3.0f);                          \
    h = fmaf(q2.x,xr0.x, fmaf(q2.y,xr0.y, fmaf(q2.z,xr0.z, h))) + q2.w;   \
    sA[BUF][kq*4+2][r0] = h > 0.0f ? h : 0.0f;                            \
    h = ((pa0.w + pe0.w) + pf0.w) * (1.0f/3.0f);                          \
    h = fmaf(q3.x,xr0.x, fmaf(q3.y,xr0.y, fmaf(q3.z,xr0.z, h))) + q3.w;   \
    sA[BUF][kq*4+3][r0] = h > 0.0f ? h : 0.0f;                            \
    sW[BUF][kq*4+0][r0] = pw0.x; sW[BUF][kq*4+1][r0] = pw0.y;             \
    sW[BUF][kq*4+2][r0] = pw0.z; sW[BUF][kq*4+3][r0] = pw0.w;             \
    h = ((pa1.x + pe1.x) + pf1.x) * (1.0f/3.0f);                          \
    h = fmaf(q0.x,xr1.x, fmaf(q0.y,xr1.y, fmaf(q0.z,xr1.z, h))) + q0.w;   \
    sA[BUF][kq*4+0][r1] = h > 0.0f ? h : 0.0f;                            \
    h = ((pa1.y + pe1.y) + pf1.y) * (1.0f/3.0f);                          \
    h = fmaf(q1.x,xr1.x, fmaf(q1.y,xr1.y, fmaf(q1.z,xr1.z, h))) + q1.w;   \
    sA[BUF][kq*4+1][r1] = h > 0.0f ? h : 0.0f;                            \
    h = ((pa1.z + pe1.z) + pf1.z) * (1.0f/3.0f);                          \
    h = fmaf(q2.x,xr1.x, fmaf(q2.y,xr1.y, fmaf(q2.z,xr1.z, h))) + q2.w;   \
    sA[BUF][kq*4+2][r1] = h > 0.0f ? h : 0.0f;                            \
    h = ((pa1.w + pe1.w) + pf1.w) * (1.0f/3.0f);                          \
    h = fmaf(q3.x,xr1.x, fmaf(q3.y,xr1.y, fmaf(q3.z,xr1.z, h))) + q3.w;   \
    sA[BUF][kq*4+3][r1] = h > 0.0f ? h : 0.0f;                            \
    sW[BUF][kq*4+0][r1] = pw1.x; sW[BUF][kq*4+1][r1] = pw1.y;             \
    sW[BUF][kq*4+2][r1] = pw1.z; sW[BUF][kq*4+3][r1] = pw1.w; }

#define FCORE(BUF) {                                                      \
    _Pragma("unroll")                                                     \
    for (int kk = 0; kk < 16; ++kk) {                                     \
        float4 a0 = *(const float4*)&sA[BUF][kk][tr*8];                   \
        float4 a1 = *(const float4*)&sA[BUF][kk][tr*8+4];                 \
        float4 c0 = *(const float4*)&sW[BUF][kk][tc*8];                   \
        float4 c1 = *(const float4*)&sW[BUF][kk][tc*8+4];                 \
        float av[8] = {a0.x,a0.y,a0.z,a0.w,a1.x,a1.y,a1.z,a1.w};          \
        float bv[8] = {c0.x,c0.y,c0.z,c0.w,c1.x,c1.y,c1.z,c1.w};          \
        _Pragma("unroll")                                                 \
        for (int i = 0; i < 8; ++i)                                       \
            _Pragma("unroll")                                             \
            for (int j = 0; j < 8; ++j)                                   \
                acc[i][j] = fmaf(av[i], bv[j], acc[i][j]);                \
    } }

    // ---- prologue: fill buffer 0 with chunk 0 ----
    TLOAD(0)
    TBUILD(0, 0)
    __syncthreads();

    // ---- pipelined kc loop: load(kc+1) || FMA(kc) ; build(kc+1) ; barrier
    for (int kc = 0; kc < 8; kc += 2) {
        TLOAD(kc + 1)               // kc <= 6, always valid
        FCORE(0)
        TBUILD(1, kc + 1)
        __syncthreads();
        if (kc + 1 < 7) TLOAD(kc + 2)
        FCORE(1)
        if (kc + 1 < 7) TBUILD(0, kc + 2)
        __syncthreads();
    }

#undef TLOAD
#undef TBUILD
#undef FCORE

    // ---- epilogue: bias + transposed store out[b][o][n] (unchanged) ----
    const int n0 = (row0 & (N_-1)) + tr*8;
    #pragma unroll
    for (int j = 0; j < 8; ++j) {
        int o = tc*8 + j;
        float bias = b2[o];
        float4 o0 = make_float4(acc[0][j]+bias, acc[1][j]+bias,
                                acc[2][j]+bias, acc[3][j]+bias);
        float4 o1 = make_float4(acc[4][j]+bias, acc[5][j]+bias,
                                acc[6][j]+bias, acc[7][j]+bias);
        float* dst = out + (((size_t)(b*OUT_ + o)) << 15) + n0;
        *(float4*)dst       = o0;
        *(float4*)(dst + 4) = o1;
    }
}

extern "C" void kernel_launch(void* const* d_in, const int* in_sizes, int n_in,
                              void* d_out, int out_size, void* d_ws, size_t ws_size,
                              hipStream_t stream) {
    const float* x        = (const float*)d_in[0];   // [B,N,3]
    const float* sx       = (const float*)d_in[1];   // [B,M,3]
    const float* features = (const float*)d_in[2];   // [B,M,C]
    const float* w1       = (const float*)d_in[3];   // [128,131]
    const float* b1       = (const float*)d_in[4];   // [128]
    const float* w2       = (const float*)d_in[5];   // [128,128]
    const float* b2       = (const float*)d_in[6];   // [128]
    float* out = (float*)d_out;                      // [B,128,N]

    char* ws = (char*)d_ws;
    // Layout:
    //   [2,6MB)     G        (4 MB)
    //   [33,49MB)   part_d
    //   [49,65MB)   part_i
    float*  G      = (float*)(ws + (2u  << 20));
    float4* part_d = (float4*)(ws + (33u << 20));
    int4*   part_i = (int4*) (ws + (33u << 20) + (16u<<20));

    nn_split_kernel <<<dim3((NQ/1024) * NSPLIT), dim3(256), 0, stream>>>(x, sx, part_d, part_i);
    pre_gemm_kernel <<<dim3(B_*M_/128), dim3(256), 0, stream>>>(features, w1, G);
    fused_tail_kernel<<<dim3(NQ/128), dim3(256), 0, stream>>>(part_d, part_i, G, x,
                                                              w1, b1, w2, b2, out);
}

// Round 2
// 267.131 us; speedup vs baseline: 1.3379x; 1.3379x over previous
//
#include <hip/hip_runtime.h>

#define B_   2
#define N_   32768
#define M_   4096
#define C_   128
#define OUT_ 128
#define IN_  131

#define NSPLIT 16
#define MCHUNK (M_ / NSPLIT)     // 256 points per split
#define NQ     (B_ * N_)         // 65536 total queries

// ---------------------------------------------------------------------------
// K1: split brute-force 3-NN, branchless top-3, explicit scalar state.
// (byte-identical — control; VALU-issue-bound at exactness-required op count)
// ---------------------------------------------------------------------------
#define NN_DECL(X)                                                        \
    float x0##X, x1##X, x2##X, xx##X;                                     \
    float bd0##X = 1e30f, bd1##X = 1e30f, bd2##X = 1e30f;                 \
    int   bi0##X = 0,     bi1##X = 0,     bi2##X = 0;

#define NN_LOAD(X, QQ) {                                                  \
    const int qi = q0 + (QQ) * 256 + t;                                   \
    x0##X = x[(size_t)qi*3+0];                                            \
    x1##X = x[(size_t)qi*3+1];                                            \
    x2##X = x[(size_t)qi*3+2];                                            \
    xx##X = __fadd_rn(__fadd_rn(__fmul_rn(x0##X,x0##X),                   \
                                __fmul_rn(x1##X,x1##X)),                  \
                      __fmul_rn(x2##X,x2##X)); }

#define NN_STEP(X) {                                                      \
    float dot = __fadd_rn(__fadd_rn(__fmul_rn(x0##X,s.x),                 \
                                    __fmul_rn(x1##X,s.y)),                \
                          __fmul_rn(x2##X,s.z));                          \
    float d2 = __fadd_rn(__fmaf_rn(-2.0f, dot, xx##X), s.w);              \
    const float k0 = bd0##X, k1 = bd1##X, k2 = bd2##X;                    \
    const bool c0 = d2 < k0, c1 = d2 < k1, c2 = d2 < k2;                  \
    bi2##X = c1 ? bi1##X : (c2 ? m : bi2##X);                             \
    bi1##X = c0 ? bi0##X : (c1 ? m : bi1##X);                             \
    bi0##X = c0 ? m : bi0##X;                                             \
    bd0##X = fminf(k0, d2);                                               \
    bd1##X = __builtin_amdgcn_fmed3f(d2, k0, k1);                         \
    bd2##X = __builtin_amdgcn_fmed3f(d2, k1, k2); }

#define NN_STORE(X, QQ) {                                                 \
    const int qi = q0 + (QQ) * 256 + t;                                   \
    part_d[(size_t)split * NQ + qi] =                                     \
        make_float4(bd0##X, bd1##X, bd2##X, 0.f);                         \
    part_i[(size_t)split * NQ + qi] =                                     \
        make_int4(bi0##X, bi1##X, bi2##X, 0); }

__global__ __launch_bounds__(256, 4) void nn_split_kernel(const float* __restrict__ x,
                                                          const float* __restrict__ sx,
                                                          float4* __restrict__ part_d,
                                                          int4* __restrict__ part_i) {
    __shared__ float4 spts[MCHUNK];   // 4 KB
    const int split = blockIdx.x & (NSPLIT - 1);
    const int qb    = blockIdx.x >> 4;
    const int q0    = qb * 1024;
    const int b     = q0 >> 15;                     // N_=32768
    const int t     = threadIdx.x;

    // stage + pack this split's points (|s|^2 in reference rounding order)
    {
        const float* sp = sx + ((size_t)b * M_ + split * MCHUNK + t) * 3;
        float s0 = sp[0], s1 = sp[1], s2 = sp[2];
        float ss = __fadd_rn(__fadd_rn(__fmul_rn(s0,s0), __fmul_rn(s1,s1)),
                             __fmul_rn(s2,s2));
        spts[t] = make_float4(s0, s1, s2, ss);
    }
    __syncthreads();

    NN_DECL(A) NN_DECL(B) NN_DECL(C) NN_DECL(D)
    NN_LOAD(A, 0) NN_LOAD(B, 1) NN_LOAD(C, 2) NN_LOAD(D, 3)

    const int m_base = split * MCHUNK;
    #pragma unroll 2
    for (int j = 0; j < MCHUNK; ++j) {
        const float4 s = spts[j];
        const int m = m_base + j;
        NN_STEP(A) NN_STEP(B) NN_STEP(C) NN_STEP(D)
    }

    NN_STORE(A, 0) NN_STORE(B, 1) NN_STORE(C, 2) NN_STORE(D, 3)
}

// ---------------------------------------------------------------------------
// K2a: G = features @ W1f^T over all B*M sampled points (8192 rows, K=128).
// (unchanged)
// ---------------------------------------------------------------------------
__global__ __launch_bounds__(256) void pre_gemm_kernel(const float* __restrict__ features,
                                                       const float* __restrict__ w1,
                                                       float* __restrict__ G) {
    __shared__ float sI[16][132];
    __shared__ float sW[16][132];
    const int row0 = blockIdx.x * 128;
    const int tid  = threadIdx.x;
    const int tr   = tid & 15;
    const int tc   = tid >> 4;
    float acc[8][8] = {};

    for (int kc = 0; kc < 8; ++kc) {
        #pragma unroll
        for (int j = 0; j < 2; ++j) {
            int id  = j * 256 + tid;
            int row = id >> 2, kq = id & 3;
            float4 g = ((const float4*)features)[(size_t)(row0 + row) * 32 + kc * 4 + kq];
            sI[kq*4+0][row] = g.x; sI[kq*4+1][row] = g.y;
            sI[kq*4+2][row] = g.z; sI[kq*4+3][row] = g.w;
        }
        {
            int o = tid >> 1, kk0 = (tid & 1) * 8;
            #pragma unroll
            for (int kk = 0; kk < 8; ++kk)
                sW[kk0+kk][o] = w1[(size_t)o * IN_ + 3 + kc*16 + kk0 + kk];
        }
        __syncthreads();
        #pragma unroll
        for (int kk = 0; kk < 16; ++kk) {
            float4 a0 = *(const float4*)&sI[kk][tr*8];
            float4 a1 = *(const float4*)&sI[kk][tr*8+4];
            float4 c0 = *(const float4*)&sW[kk][tc*8];
            float4 c1 = *(const float4*)&sW[kk][tc*8+4];
            float av[8] = {a0.x,a0.y,a0.z,a0.w,a1.x,a1.y,a1.z,a1.w};
            float bv[8] = {c0.x,c0.y,c0.z,c0.w,c1.x,c1.y,c1.z,c1.w};
            #pragma unroll
            for (int i = 0; i < 8; ++i)
                #pragma unroll
                for (int j = 0; j < 8; ++j)
                    acc[i][j] = fmaf(av[i], bv[j], acc[i][j]);
        }
        __syncthreads();
    }

    #pragma unroll
    for (int i = 0; i < 8; ++i) {
        int r = row0 + tr*8 + i;
        float4 o0 = make_float4(acc[i][0], acc[i][1], acc[i][2], acc[i][3]);
        float4 o1 = make_float4(acc[i][4], acc[i][5], acc[i][6], acc[i][7]);
        ((float4*)G)[(size_t)r * 32 + tc*2 + 0] = o0;
        ((float4*)G)[(size_t)r * 32 + tc*2 + 1] = o1;
    }
}

// ---------------------------------------------------------------------------
// K3 (fused tail, v2): round-0 single-buffer structure + two surgical fixes.
//   (1) REGISTER PREFETCH, single LDS buffer: chunk kc+1's 6 G-gathers +
//       2 w2 loads are issued into registers BEFORE FCORE(kc); the LDS
//       writes happen after the read-barrier. Same 2 barriers/chunk as the
//       proven version; gather latency (~500cy L2/L3) hides under ~2048cy
//       of FMA issue. Cost: +32 VGPR, NOT the 256-VGPR/spill disaster of
//       the double-buffered attempt (WRITE_SIZE 310MB was scratch).
//   (2) XCD-BATCH SWIZZLE (bijective, 512 blocks, dispatch = bid%8 per XCD):
//       XCDs 0-3 get batch-0 blocks, XCDs 4-7 batch-1 -> per-XCD gather
//       working set = 4MB = one L2 (was 8MB -> thrash -> L3 latency).
//   All H/FMA/merge/epilogue arithmetic character-identical to round-0.
// ---------------------------------------------------------------------------
__global__ __launch_bounds__(256) void fused_tail_kernel(const float4* __restrict__ part_d,
                                                         const int4* __restrict__ part_i,
                                                         const float* __restrict__ G,
                                                         const float* __restrict__ x,
                                                         const float* __restrict__ w1,
                                                         const float* __restrict__ b1,
                                                         const float* __restrict__ w2,
                                                         const float* __restrict__ b2,
                                                         float* __restrict__ out) {
    __shared__ float  sA[16][132];    // H chunk [k][row]
    __shared__ float  sW[16][132];    // w2 chunk [k][out]
    __shared__ int4   sIdx[128];      // merged top-3 per query
    __shared__ float4 sX[128];        // query coords
    __shared__ float4 sWX[128];       // (wx0,wx1,wx2,b1) per channel

    // XCD-batch swizzle: bid -> (xcd = bid&7, slot = bid>>3);
    // logical block = (xcd>>2)*256 + slot*4 + (xcd&3). Bijective on [0,512).
    const int bid  = blockIdx.x;
    const int xcd  = bid & 7;
    const int slot = bid >> 3;
    const int lb   = ((xcd >> 2) << 8) + slot * 4 + (xcd & 3);
    const int row0 = lb * 128;

    const int tid  = threadIdx.x;
    const int tr   = tid & 15;
    const int tc   = tid >> 4;
    const int b    = row0 >> 15;

    // ---- Phase 0: merge (threads 0-127) || stage w1-xyz table (128-255) ----
    if (tid < 128) {
        const int q = row0 + tid;
        float b0 = 1e30f, b1v = 1e30f, b2v = 1e30f;
        int   i0 = 0,     i1 = 0,      i2 = 0;
        #pragma unroll
        for (int s = 0; s < NSPLIT; ++s) {
            float4 d = part_d[(size_t)s * NQ + q];
            int4   i = part_i[(size_t)s * NQ + q];
            if (d.x < b2v) { if (d.x < b1v) { b2v=b1v; i2=i1;
                if (d.x < b0) { b1v=b0; i1=i0; b0=d.x; i0=i.x; }
                else          { b1v=d.x; i1=i.x; } } else { b2v=d.x; i2=i.x; } }
            if (d.y < b2v) { if (d.y < b1v) { b2v=b1v; i2=i1;
                if (d.y < b0) { b1v=b0; i1=i0; b0=d.y; i0=i.y; }
                else          { b1v=d.y; i1=i.y; } } else { b2v=d.y; i2=i.y; } }
            if (d.z < b2v) { if (d.z < b1v) { b2v=b1v; i2=i1;
                if (d.z < b0) { b1v=b0; i1=i0; b0=d.z; i0=i.z; }
                else          { b1v=d.z; i1=i.z; } } else { b2v=d.z; i2=i.z; } }
        }
        sIdx[tid] = make_int4(i0, i1, i2, 0);
        const float* xp = x + (size_t)q * 3;
        sX[tid] = make_float4(xp[0], xp[1], xp[2], 0.f);
    } else {
        const int c = tid - 128;
        sWX[c] = make_float4(w1[(size_t)c*IN_+0], w1[(size_t)c*IN_+1],
                             w1[(size_t)c*IN_+2], b1[c]);
    }
    __syncthreads();

    // ---- hoisted per-thread constants (sIdx/sX fixed after phase 0) ----
    const float4* gb   = (const float4*)G + (size_t)b * M_ * 32;
    const float4* w2v4 = (const float4*)w2;
    const int r0 = tid >> 2;        // j=0 row (query in [0,64))
    const int r1 = 64 + r0;         // j=1 row
    const int kq = tid & 3;
    const int4   v0  = sIdx[r0], v1  = sIdx[r1];
    const float4 xr0 = sX[r0],   xr1 = sX[r1];

    float acc[8][8] = {};
    float4 pa0, pe0, pf0, pw0, pa1, pe1, pf1, pw1;   // prefetch regs (32 VGPR)

#define TLOAD(KC) {                                                       \
    const int c4 = (KC)*4 + kq;                                           \
    pa0 = gb[(size_t)v0.x*32 + c4];                                       \
    pe0 = gb[(size_t)v0.y*32 + c4];                                       \
    pf0 = gb[(size_t)v0.z*32 + c4];                                       \
    pa1 = gb[(size_t)v1.x*32 + c4];                                       \
    pe1 = gb[(size_t)v1.y*32 + c4];                                       \
    pf1 = gb[(size_t)v1.z*32 + c4];                                       \
    pw0 = w2v4[(size_t)r0*32 + c4];                                       \
    pw1 = w2v4[(size_t)r1*32 + c4]; }

#define TBUILD(KC) {                                                      \
    const int c4 = (KC)*4 + kq;                                           \
    const float4 q0 = sWX[c4*4+0], q1 = sWX[c4*4+1];                      \
    const float4 q2 = sWX[c4*4+2], q3 = sWX[c4*4+3];                      \
    float h;                                                              \
    h = ((pa0.x + pe0.x) + pf0.x) * (1.0f/3.0f);                          \
    h = fmaf(q0.x,xr0.x, fmaf(q0.y,xr0.y, fmaf(q0.z,xr0.z, h))) + q0.w;   \
    sA[kq*4+0][r0] = h > 0.0f ? h : 0.0f;                                 \
    h = ((pa0.y + pe0.y) + pf0.y) * (1.0f/3.0f);                          \
    h = fmaf(q1.x,xr0.x, fmaf(q1.y,xr0.y, fmaf(q1.z,xr0.z, h))) + q1.w;   \
    sA[kq*4+1][r0] = h > 0.0f ? h : 0.0f;                                 \
    h = ((pa0.z + pe0.z) + pf0.z) * (1.0f/3.0f);                          \
    h = fmaf(q2.x,xr0.x, fmaf(q2.y,xr0.y, fmaf(q2.z,xr0.z, h))) + q2.w;   \
    sA[kq*4+2][r0] = h > 0.0f ? h : 0.0f;                                 \
    h = ((pa0.w + pe0.w) + pf0.w) * (1.0f/3.0f);                          \
    h = fmaf(q3.x,xr0.x, fmaf(q3.y,xr0.y, fmaf(q3.z,xr0.z, h))) + q3.w;   \
    sA[kq*4+3][r0] = h > 0.0f ? h : 0.0f;                                 \
    sW[kq*4+0][r0] = pw0.x; sW[kq*4+1][r0] = pw0.y;                       \
    sW[kq*4+2][r0] = pw0.z; sW[kq*4+3][r0] = pw0.w;                       \
    h = ((pa1.x + pe1.x) + pf1.x) * (1.0f/3.0f);                          \
    h = fmaf(q0.x,xr1.x, fmaf(q0.y,xr1.y, fmaf(q0.z,xr1.z, h))) + q0.w;   \
    sA[kq*4+0][r1] = h > 0.0f ? h : 0.0f;                                 \
    h = ((pa1.y + pe1.y) + pf1.y) * (1.0f/3.0f);                          \
    h = fmaf(q1.x,xr1.x, fmaf(q1.y,xr1.y, fmaf(q1.z,xr1.z, h))) + q1.w;   \
    sA[kq*4+1][r1] = h > 0.0f ? h : 0.0f;                                 \
    h = ((pa1.z + pe1.z) + pf1.z) * (1.0f/3.0f);                          \
    h = fmaf(q2.x,xr1.x, fmaf(q2.y,xr1.y, fmaf(q2.z,xr1.z, h))) + q2.w;   \
    sA[kq*4+2][r1] = h > 0.0f ? h : 0.0f;                                 \
    h = ((pa1.w + pe1.w) + pf1.w) * (1.0f/3.0f);                          \
    h = fmaf(q3.x,xr1.x, fmaf(q3.y,xr1.y, fmaf(q3.z,xr1.z, h))) + q3.w;   \
    sA[kq*4+3][r1] = h > 0.0f ? h : 0.0f;                                 \
    sW[kq*4+0][r1] = pw1.x; sW[kq*4+1][r1] = pw1.y;                       \
    sW[kq*4+2][r1] = pw1.z; sW[kq*4+3][r1] = pw1.w; }

    // ---- prologue: chunk 0 into LDS ----
    TLOAD(0)
    TBUILD(0)
    __syncthreads();

    // ---- kc loop: issue loads(kc+1) || FCORE(kc); barrier; write(kc+1) ----
    for (int kc = 0; kc < 8; ++kc) {
        if (kc < 7) TLOAD(kc + 1)          // overlap with FMA core below
        #pragma unroll
        for (int kk = 0; kk < 16; ++kk) {
            float4 a0 = *(const float4*)&sA[kk][tr*8];
            float4 a1 = *(const float4*)&sA[kk][tr*8+4];
            float4 c0 = *(const float4*)&sW[kk][tc*8];
            float4 c1 = *(const float4*)&sW[kk][tc*8+4];
            float av[8] = {a0.x,a0.y,a0.z,a0.w,a1.x,a1.y,a1.z,a1.w};
            float bv[8] = {c0.x,c0.y,c0.z,c0.w,c1.x,c1.y,c1.z,c1.w};
            #pragma unroll
            for (int i = 0; i < 8; ++i)
                #pragma unroll
                for (int j = 0; j < 8; ++j)
                    acc[i][j] = fmaf(av[i], bv[j], acc[i][j]);
        }
        __syncthreads();                   // all FCORE reads done
        if (kc < 7) {
            TBUILD(kc + 1)                 // regs -> LDS (single buffer)
            __syncthreads();               // writes visible for next FCORE
        }
    }

#undef TLOAD
#undef TBUILD

    // ---- epilogue: bias + transposed store out[b][o][n] (unchanged) ----
    const int n0 = (row0 & (N_-1)) + tr*8;
    #pragma unroll
    for (int j = 0; j < 8; ++j) {
        int o = tc*8 + j;
        float bias = b2[o];
        float4 o0 = make_float4(acc[0][j]+bias, acc[1][j]+bias,
                                acc[2][j]+bias, acc[3][j]+bias);
        float4 o1 = make_float4(acc[4][j]+bias, acc[5][j]+bias,
                                acc[6][j]+bias, acc[7][j]+bias);
        float* dst = out + (((size_t)(b*OUT_ + o)) << 15) + n0;
        *(float4*)dst       = o0;
        *(float4*)(dst + 4) = o1;
    }
}

extern "C" void kernel_launch(void* const* d_in, const int* in_sizes, int n_in,
                              void* d_out, int out_size, void* d_ws, size_t ws_size,
                              hipStream_t stream) {
    const float* x        = (const float*)d_in[0];   // [B,N,3]
    const float* sx       = (const float*)d_in[1];   // [B,M,3]
    const float* features = (const float*)d_in[2];   // [B,M,C]
    const float* w1       = (const float*)d_in[3];   // [128,131]
    const float* b1       = (const float*)d_in[4];   // [128]
    const float* w2       = (const float*)d_in[5];   // [128,128]
    const float* b2       = (const float*)d_in[6];   // [128]
    float* out = (float*)d_out;                      // [B,128,N]

    char* ws = (char*)d_ws;
    // Layout:
    //   [2,6MB)     G        (4 MB)
    //   [33,49MB)   part_d
    //   [49,65MB)   part_i
    float*  G      = (float*)(ws + (2u  << 20));
    float4* part_d = (float4*)(ws + (33u << 20));
    int4*   part_i = (int4*) (ws + (33u << 20) + (16u<<20));

    nn_split_kernel <<<dim3((NQ/1024) * NSPLIT), dim3(256), 0, stream>>>(x, sx, part_d, part_i);
    pre_gemm_kernel <<<dim3(B_*M_/128), dim3(256), 0, stream>>>(features, w1, G);
    fused_tail_kernel<<<dim3(NQ/128), dim3(256), 0, stream>>>(part_d, part_i, G, x,
                                                              w1, b1, w2, b2, out);
}

// Round 3
// 233.794 us; speedup vs baseline: 1.5287x; 1.1426x over previous
//
#include <hip/hip_runtime.h>

#define B_   2
#define N_   32768
#define M_   4096
#define C_   128
#define OUT_ 128
#define IN_  131

#define NSPLIT 16
#define MCHUNK (M_ / NSPLIT)     // 256 points per split
#define NQ     (B_ * N_)         // 65536 total queries
#define NNBLK  ((NQ / 1024) * NSPLIT)   // 1024 NN blocks
#define PREBLK (B_ * M_ / 128)          // 64 pre-GEMM blocks

// ---------------------------------------------------------------------------
// K1 (fused front): blocks [0,1024) = split brute-force 3-NN (byte-identical
// arithmetic — VALU-issue-floor control); blocks [1024,1088) = pre-GEMM
// G = features @ W1f^T. The two are data-independent; fusing hides the
// serial ~10us pre_gemm bubble under the VALU-bound NN scan.
// part_i packed as ushort4 (idx < 4096 fits 16 bits exactly): 32->24 MB
// round-trip traffic.
// ---------------------------------------------------------------------------
#define NN_DECL(X)                                                        \
    float x0##X, x1##X, x2##X, xx##X;                                     \
    float bd0##X = 1e30f, bd1##X = 1e30f, bd2##X = 1e30f;                 \
    int   bi0##X = 0,     bi1##X = 0,     bi2##X = 0;

#define NN_LOAD(X, QQ) {                                                  \
    const int qi = q0 + (QQ) * 256 + t;                                   \
    x0##X = x[(size_t)qi*3+0];                                            \
    x1##X = x[(size_t)qi*3+1];                                            \
    x2##X = x[(size_t)qi*3+2];                                            \
    xx##X = __fadd_rn(__fadd_rn(__fmul_rn(x0##X,x0##X),                   \
                                __fmul_rn(x1##X,x1##X)),                  \
                      __fmul_rn(x2##X,x2##X)); }

#define NN_STEP(X) {                                                      \
    float dot = __fadd_rn(__fadd_rn(__fmul_rn(x0##X,s.x),                 \
                                    __fmul_rn(x1##X,s.y)),                \
                          __fmul_rn(x2##X,s.z));                          \
    float d2 = __fadd_rn(__fmaf_rn(-2.0f, dot, xx##X), s.w);              \
    const float k0 = bd0##X, k1 = bd1##X, k2 = bd2##X;                    \
    const bool c0 = d2 < k0, c1 = d2 < k1, c2 = d2 < k2;                  \
    bi2##X = c1 ? bi1##X : (c2 ? m : bi2##X);                             \
    bi1##X = c0 ? bi0##X : (c1 ? m : bi1##X);                             \
    bi0##X = c0 ? m : bi0##X;                                             \
    bd0##X = fminf(k0, d2);                                               \
    bd1##X = __builtin_amdgcn_fmed3f(d2, k0, k1);                         \
    bd2##X = __builtin_amdgcn_fmed3f(d2, k1, k2); }

#define NN_STORE(X, QQ) {                                                 \
    const int qi = q0 + (QQ) * 256 + t;                                   \
    part_d[(size_t)split * NQ + qi] =                                     \
        make_float4(bd0##X, bd1##X, bd2##X, 0.f);                         \
    part_i[(size_t)split * NQ + qi] =                                     \
        make_ushort4((unsigned short)bi0##X, (unsigned short)bi1##X,      \
                     (unsigned short)bi2##X, 0); }

__global__ __launch_bounds__(256, 4) void fused_front_kernel(const float* __restrict__ x,
                                                             const float* __restrict__ sx,
                                                             float4* __restrict__ part_d,
                                                             ushort4* __restrict__ part_i,
                                                             const float* __restrict__ features,
                                                             const float* __restrict__ w1,
                                                             float* __restrict__ G) {
    __shared__ float4 spts[MCHUNK];   // 4 KB   (NN path)
    __shared__ float  sI[16][132];    // 8.25 KB (pre path)
    __shared__ float  sW[16][132];    // 8.25 KB (pre path)
    const int tid = threadIdx.x;

    if (blockIdx.x < NNBLK) {
        // ---------------- NN path (byte-identical arithmetic) ----------------
        const int split = blockIdx.x & (NSPLIT - 1);
        const int qb    = blockIdx.x >> 4;
        const int q0    = qb * 1024;
        const int b     = q0 >> 15;                     // N_=32768
        const int t     = tid;

        {
            const float* sp = sx + ((size_t)b * M_ + split * MCHUNK + t) * 3;
            float s0 = sp[0], s1 = sp[1], s2 = sp[2];
            float ss = __fadd_rn(__fadd_rn(__fmul_rn(s0,s0), __fmul_rn(s1,s1)),
                                 __fmul_rn(s2,s2));
            spts[t] = make_float4(s0, s1, s2, ss);
        }
        __syncthreads();

        NN_DECL(A) NN_DECL(B) NN_DECL(C) NN_DECL(D)
        NN_LOAD(A, 0) NN_LOAD(B, 1) NN_LOAD(C, 2) NN_LOAD(D, 3)

        const int m_base = split * MCHUNK;
        #pragma unroll 2
        for (int j = 0; j < MCHUNK; ++j) {
            const float4 s = spts[j];
            const int m = m_base + j;
            NN_STEP(A) NN_STEP(B) NN_STEP(C) NN_STEP(D)
        }

        NN_STORE(A, 0) NN_STORE(B, 1) NN_STORE(C, 2) NN_STORE(D, 3)
    } else {
        // ---------------- pre-GEMM path (unchanged arithmetic) ---------------
        const int row0 = (blockIdx.x - NNBLK) * 128;
        const int tr   = tid & 15;
        const int tc   = tid >> 4;
        float acc[8][8] = {};

        for (int kc = 0; kc < 8; ++kc) {
            #pragma unroll
            for (int j = 0; j < 2; ++j) {
                int id  = j * 256 + tid;
                int row = id >> 2, kq = id & 3;
                float4 g = ((const float4*)features)[(size_t)(row0 + row) * 32 + kc * 4 + kq];
                sI[kq*4+0][row] = g.x; sI[kq*4+1][row] = g.y;
                sI[kq*4+2][row] = g.z; sI[kq*4+3][row] = g.w;
            }
            {
                int o = tid >> 1, kk0 = (tid & 1) * 8;
                #pragma unroll
                for (int kk = 0; kk < 8; ++kk)
                    sW[kk0+kk][o] = w1[(size_t)o * IN_ + 3 + kc*16 + kk0 + kk];
            }
            __syncthreads();
            #pragma unroll
            for (int kk = 0; kk < 16; ++kk) {
                float4 a0 = *(const float4*)&sI[kk][tr*8];
                float4 a1 = *(const float4*)&sI[kk][tr*8+4];
                float4 c0 = *(const float4*)&sW[kk][tc*8];
                float4 c1 = *(const float4*)&sW[kk][tc*8+4];
                float av[8] = {a0.x,a0.y,a0.z,a0.w,a1.x,a1.y,a1.z,a1.w};
                float bv[8] = {c0.x,c0.y,c0.z,c0.w,c1.x,c1.y,c1.z,c1.w};
                #pragma unroll
                for (int i = 0; i < 8; ++i)
                    #pragma unroll
                    for (int j = 0; j < 8; ++j)
                        acc[i][j] = fmaf(av[i], bv[j], acc[i][j]);
            }
            __syncthreads();
        }

        #pragma unroll
        for (int i = 0; i < 8; ++i) {
            int r = row0 + tr*8 + i;
            float4 o0 = make_float4(acc[i][0], acc[i][1], acc[i][2], acc[i][3]);
            float4 o1 = make_float4(acc[i][4], acc[i][5], acc[i][6], acc[i][7]);
            ((float4*)G)[(size_t)r * 32 + tc*2 + 0] = o0;
            ((float4*)G)[(size_t)r * 32 + tc*2 + 1] = o1;
        }
    }
}

// ---------------------------------------------------------------------------
// K3 (fused tail): EXACT round-0 structure (proven 246us total) — merge +
// H-on-the-fly + gemm2 + transposed store. Only change: part_i is ushort4.
// ---------------------------------------------------------------------------
__global__ __launch_bounds__(256) void fused_tail_kernel(const float4* __restrict__ part_d,
                                                         const ushort4* __restrict__ part_i,
                                                         const float* __restrict__ G,
                                                         const float* __restrict__ x,
                                                         const float* __restrict__ w1,
                                                         const float* __restrict__ b1,
                                                         const float* __restrict__ w2,
                                                         const float* __restrict__ b2,
                                                         float* __restrict__ out) {
    __shared__ float  sA[16][132];    // H chunk [k][row]
    __shared__ float  sW[16][132];    // w2 chunk [k][out]
    __shared__ int4   sIdx[128];      // merged top-3 per query
    __shared__ float4 sX[128];        // query coords
    __shared__ float4 sWX[128];       // (wx0,wx1,wx2,b1) per channel
    const int row0 = blockIdx.x * 128;
    const int tid  = threadIdx.x;
    const int tr   = tid & 15;
    const int tc   = tid >> 4;
    const int b    = row0 >> 15;

    // ---- Phase 0: merge (threads 0-127) || stage w1-xyz table (128-255) ----
    if (tid < 128) {
        const int q = row0 + tid;
        float b0 = 1e30f, b1v = 1e30f, b2v = 1e30f;
        int   i0 = 0,     i1 = 0,      i2 = 0;
        #pragma unroll
        for (int s = 0; s < NSPLIT; ++s) {
            float4  d = part_d[(size_t)s * NQ + q];
            ushort4 u = part_i[(size_t)s * NQ + q];
            const int ux = u.x, uy = u.y, uz = u.z;
            if (d.x < b2v) { if (d.x < b1v) { b2v=b1v; i2=i1;
                if (d.x < b0) { b1v=b0; i1=i0; b0=d.x; i0=ux; }
                else          { b1v=d.x; i1=ux; } } else { b2v=d.x; i2=ux; } }
            if (d.y < b2v) { if (d.y < b1v) { b2v=b1v; i2=i1;
                if (d.y < b0) { b1v=b0; i1=i0; b0=d.y; i0=uy; }
                else          { b1v=d.y; i1=uy; } } else { b2v=d.y; i2=uy; } }
            if (d.z < b2v) { if (d.z < b1v) { b2v=b1v; i2=i1;
                if (d.z < b0) { b1v=b0; i1=i0; b0=d.z; i0=uz; }
                else          { b1v=d.z; i1=uz; } } else { b2v=d.z; i2=uz; } }
        }
        sIdx[tid] = make_int4(i0, i1, i2, 0);
        const float* xp = x + (size_t)q * 3;
        sX[tid] = make_float4(xp[0], xp[1], xp[2], 0.f);
    } else {
        const int c = tid - 128;
        sWX[c] = make_float4(w1[(size_t)c*IN_+0], w1[(size_t)c*IN_+1],
                             w1[(size_t)c*IN_+2], b1[c]);
    }
    __syncthreads();

    // ---- kc loop: build H chunk in LDS + stage w2 chunk, then FMA core ----
    const float4* gb = (const float4*)G + (size_t)b * M_ * 32;
    float acc[8][8] = {};
    for (int kc = 0; kc < 8; ++kc) {
        #pragma unroll
        for (int j = 0; j < 2; ++j) {
            int id  = j * 256 + tid;
            int row = id >> 2, kq = id & 3;
            const int c4 = kc * 4 + kq;          // channel-group [0,32)
            int4 v = sIdx[row];
            float4 a = gb[(size_t)v.x * 32 + c4];
            float4 e = gb[(size_t)v.y * 32 + c4];
            float4 f = gb[(size_t)v.z * 32 + c4];
            float4 xr = sX[row];
            float4 w0  = sWX[c4*4+0], w1v = sWX[c4*4+1];
            float4 w2v = sWX[c4*4+2], w3  = sWX[c4*4+3];
            float h;
            h = ((a.x + e.x) + f.x) * (1.0f/3.0f);
            h = fmaf(w0.x,xr.x, fmaf(w0.y,xr.y, fmaf(w0.z,xr.z, h))) + w0.w;
            sA[kq*4+0][row] = h > 0.0f ? h : 0.0f;
            h = ((a.y + e.y) + f.y) * (1.0f/3.0f);
            h = fmaf(w1v.x,xr.x, fmaf(w1v.y,xr.y, fmaf(w1v.z,xr.z, h))) + w1v.w;
            sA[kq*4+1][row] = h > 0.0f ? h : 0.0f;
            h = ((a.z + e.z) + f.z) * (1.0f/3.0f);
            h = fmaf(w2v.x,xr.x, fmaf(w2v.y,xr.y, fmaf(w2v.z,xr.z, h))) + w2v.w;
            sA[kq*4+2][row] = h > 0.0f ? h : 0.0f;
            h = ((a.w + e.w) + f.w) * (1.0f/3.0f);
            h = fmaf(w3.x,xr.x, fmaf(w3.y,xr.y, fmaf(w3.z,xr.z, h))) + w3.w;
            sA[kq*4+3][row] = h > 0.0f ? h : 0.0f;
            // w2 chunk (row = output channel here)
            float4 hh = ((const float4*)w2)[(size_t)row * 32 + kc * 4 + kq];
            sW[kq*4+0][row] = hh.x; sW[kq*4+1][row] = hh.y;
            sW[kq*4+2][row] = hh.z; sW[kq*4+3][row] = hh.w;
        }
        __syncthreads();
        #pragma unroll
        for (int kk = 0; kk < 16; ++kk) {
            float4 a0 = *(const float4*)&sA[kk][tr*8];
            float4 a1 = *(const float4*)&sA[kk][tr*8+4];
            float4 c0 = *(const float4*)&sW[kk][tc*8];
            float4 c1 = *(const float4*)&sW[kk][tc*8+4];
            float av[8] = {a0.x,a0.y,a0.z,a0.w,a1.x,a1.y,a1.z,a1.w};
            float bv[8] = {c0.x,c0.y,c0.z,c0.w,c1.x,c1.y,c1.z,c1.w};
            #pragma unroll
            for (int i = 0; i < 8; ++i)
                #pragma unroll
                for (int j = 0; j < 8; ++j)
                    acc[i][j] = fmaf(av[i], bv[j], acc[i][j]);
        }
        __syncthreads();
    }

    // ---- epilogue: bias + transposed store out[b][o][n] ----
    const int n0 = (row0 & (N_-1)) + tr*8;
    #pragma unroll
    for (int j = 0; j < 8; ++j) {
        int o = tc*8 + j;
        float bias = b2[o];
        float4 o0 = make_float4(acc[0][j]+bias, acc[1][j]+bias,
                                acc[2][j]+bias, acc[3][j]+bias);
        float4 o1 = make_float4(acc[4][j]+bias, acc[5][j]+bias,
                                acc[6][j]+bias, acc[7][j]+bias);
        float* dst = out + (((size_t)(b*OUT_ + o)) << 15) + n0;
        *(float4*)dst       = o0;
        *(float4*)(dst + 4) = o1;
    }
}

extern "C" void kernel_launch(void* const* d_in, const int* in_sizes, int n_in,
                              void* d_out, int out_size, void* d_ws, size_t ws_size,
                              hipStream_t stream) {
    const float* x        = (const float*)d_in[0];   // [B,N,3]
    const float* sx       = (const float*)d_in[1];   // [B,M,3]
    const float* features = (const float*)d_in[2];   // [B,M,C]
    const float* w1       = (const float*)d_in[3];   // [128,131]
    const float* b1       = (const float*)d_in[4];   // [128]
    const float* w2       = (const float*)d_in[5];   // [128,128]
    const float* b2       = (const float*)d_in[6];   // [128]
    float* out = (float*)d_out;                      // [B,128,N]

    char* ws = (char*)d_ws;
    // Layout:
    //   [2,6MB)     G        (4 MB)
    //   [33,49MB)   part_d   (16 MB)
    //   [49,57MB)   part_i   (8 MB, ushort4)
    float*   G      = (float*)  (ws + (2u  << 20));
    float4*  part_d = (float4*) (ws + (33u << 20));
    ushort4* part_i = (ushort4*)(ws + (33u << 20) + (16u<<20));

    fused_front_kernel<<<dim3(NNBLK + PREBLK), dim3(256), 0, stream>>>(x, sx, part_d, part_i,
                                                                      features, w1, G);
    fused_tail_kernel <<<dim3(NQ/128), dim3(256), 0, stream>>>(part_d, part_i, G, x,
                                                               w1, b1, w2, b2, out);
}

// Round 5
// 230.970 us; speedup vs baseline: 1.5474x; 1.0122x over previous
//
#include <hip/hip_runtime.h>

#define B_   2
#define N_   32768
#define M_   4096
#define C_   128
#define OUT_ 128
#define IN_  131

#define NSPLIT 16
#define MCHUNK (M_ / NSPLIT)     // 256 points per split
#define NQ     (B_ * N_)         // 65536 total queries
#define NNBLK  ((NQ / 1024) * NSPLIT)   // 1024 NN blocks
#define PREBLK (B_ * M_ / 128)          // 64 pre-GEMM blocks
#define QBLK   64                       // tail queries per block (was 128)

// ---------------------------------------------------------------------------
// K1 (fused front): blocks [0,1024) = split brute-force 3-NN (byte-identical
// arithmetic — VALU-issue-floor control); blocks [1024,1088) = pre-GEMM
// G = features @ W1f^T. part_i packed ushort4. (unchanged from round 3)
// ---------------------------------------------------------------------------
#define NN_DECL(X)                                                        \
    float x0##X, x1##X, x2##X, xx##X;                                     \
    float bd0##X = 1e30f, bd1##X = 1e30f, bd2##X = 1e30f;                 \
    int   bi0##X = 0,     bi1##X = 0,     bi2##X = 0;

#define NN_LOAD(X, QQ) {                                                  \
    const int qi = q0 + (QQ) * 256 + t;                                   \
    x0##X = x[(size_t)qi*3+0];                                            \
    x1##X = x[(size_t)qi*3+1];                                            \
    x2##X = x[(size_t)qi*3+2];                                            \
    xx##X = __fadd_rn(__fadd_rn(__fmul_rn(x0##X,x0##X),                   \
                                __fmul_rn(x1##X,x1##X)),                  \
                      __fmul_rn(x2##X,x2##X)); }

#define NN_STEP(X) {                                                      \
    float dot = __fadd_rn(__fadd_rn(__fmul_rn(x0##X,s.x),                 \
                                    __fmul_rn(x1##X,s.y)),                \
                          __fmul_rn(x2##X,s.z));                          \
    float d2 = __fadd_rn(__fmaf_rn(-2.0f, dot, xx##X), s.w);              \
    const float k0 = bd0##X, k1 = bd1##X, k2 = bd2##X;                    \
    const bool c0 = d2 < k0, c1 = d2 < k1, c2 = d2 < k2;                  \
    bi2##X = c1 ? bi1##X : (c2 ? m : bi2##X);                             \
    bi1##X = c0 ? bi0##X : (c1 ? m : bi1##X);                             \
    bi0##X = c0 ? m : bi0##X;                                             \
    bd0##X = fminf(k0, d2);                                               \
    bd1##X = __builtin_amdgcn_fmed3f(d2, k0, k1);                         \
    bd2##X = __builtin_amdgcn_fmed3f(d2, k1, k2); }

#define NN_STORE(X, QQ) {                                                 \
    const int qi = q0 + (QQ) * 256 + t;                                   \
    part_d[(size_t)split * NQ + qi] =                                     \
        make_float4(bd0##X, bd1##X, bd2##X, 0.f);                         \
    part_i[(size_t)split * NQ + qi] =                                     \
        make_ushort4((unsigned short)bi0##X, (unsigned short)bi1##X,      \
                     (unsigned short)bi2##X, 0); }

__global__ __launch_bounds__(256, 4) void fused_front_kernel(const float* __restrict__ x,
                                                             const float* __restrict__ sx,
                                                             float4* __restrict__ part_d,
                                                             ushort4* __restrict__ part_i,
                                                             const float* __restrict__ features,
                                                             const float* __restrict__ w1,
                                                             float* __restrict__ G) {
    __shared__ float4 spts[MCHUNK];   // 4 KB   (NN path)
    __shared__ float  sI[16][132];    // 8.25 KB (pre path)
    __shared__ float  sW[16][132];    // 8.25 KB (pre path)
    const int tid = threadIdx.x;

    if (blockIdx.x < NNBLK) {
        // ---------------- NN path (byte-identical arithmetic) ----------------
        const int split = blockIdx.x & (NSPLIT - 1);
        const int qb    = blockIdx.x >> 4;
        const int q0    = qb * 1024;
        const int b     = q0 >> 15;                     // N_=32768
        const int t     = tid;

        {
            const float* sp = sx + ((size_t)b * M_ + split * MCHUNK + t) * 3;
            float s0 = sp[0], s1 = sp[1], s2 = sp[2];
            float ss = __fadd_rn(__fadd_rn(__fmul_rn(s0,s0), __fmul_rn(s1,s1)),
                                 __fmul_rn(s2,s2));
            spts[t] = make_float4(s0, s1, s2, ss);
        }
        __syncthreads();

        NN_DECL(A) NN_DECL(B) NN_DECL(C) NN_DECL(D)
        NN_LOAD(A, 0) NN_LOAD(B, 1) NN_LOAD(C, 2) NN_LOAD(D, 3)

        const int m_base = split * MCHUNK;
        #pragma unroll 2
        for (int j = 0; j < MCHUNK; ++j) {
            const float4 s = spts[j];
            const int m = m_base + j;
            NN_STEP(A) NN_STEP(B) NN_STEP(C) NN_STEP(D)
        }

        NN_STORE(A, 0) NN_STORE(B, 1) NN_STORE(C, 2) NN_STORE(D, 3)
    } else {
        // ---------------- pre-GEMM path (unchanged arithmetic) ---------------
        const int row0 = (blockIdx.x - NNBLK) * 128;
        const int tr   = tid & 15;
        const int tc   = tid >> 4;
        float acc[8][8] = {};

        for (int kc = 0; kc < 8; ++kc) {
            #pragma unroll
            for (int j = 0; j < 2; ++j) {
                int id  = j * 256 + tid;
                int row = id >> 2, kq = id & 3;
                float4 g = ((const float4*)features)[(size_t)(row0 + row) * 32 + kc * 4 + kq];
                sI[kq*4+0][row] = g.x; sI[kq*4+1][row] = g.y;
                sI[kq*4+2][row] = g.z; sI[kq*4+3][row] = g.w;
            }
            {
                int o = tid >> 1, kk0 = (tid & 1) * 8;
                #pragma unroll
                for (int kk = 0; kk < 8; ++kk)
                    sW[kk0+kk][o] = w1[(size_t)o * IN_ + 3 + kc*16 + kk0 + kk];
            }
            __syncthreads();
            #pragma unroll
            for (int kk = 0; kk < 16; ++kk) {
                float4 a0 = *(const float4*)&sI[kk][tr*8];
                float4 a1 = *(const float4*)&sI[kk][tr*8+4];
                float4 c0 = *(const float4*)&sW[kk][tc*8];
                float4 c1 = *(const float4*)&sW[kk][tc*8+4];
                float av[8] = {a0.x,a0.y,a0.z,a0.w,a1.x,a1.y,a1.z,a1.w};
                float bv[8] = {c0.x,c0.y,c0.z,c0.w,c1.x,c1.y,c1.z,c1.w};
                #pragma unroll
                for (int i = 0; i < 8; ++i)
                    #pragma unroll
                    for (int j = 0; j < 8; ++j)
                        acc[i][j] = fmaf(av[i], bv[j], acc[i][j]);
            }
            __syncthreads();
        }

        #pragma unroll
        for (int i = 0; i < 8; ++i) {
            int r = row0 + tr*8 + i;
            float4 o0 = make_float4(acc[i][0], acc[i][1], acc[i][2], acc[i][3]);
            float4 o1 = make_float4(acc[i][4], acc[i][5], acc[i][6], acc[i][7]);
            ((float4*)G)[(size_t)r * 32 + tc*2 + 0] = o0;
            ((float4*)G)[(size_t)r * 32 + tc*2 + 1] = o1;
        }
    }
}

// ---------------------------------------------------------------------------
// K3 (fused tail, QBLK=64): same structure/arithmetic as the proven tail but
// 64 queries per block -> 1024 blocks = 4 blocks/CU (was 2). The chunk-loop's
// serial {gather -> LDS -> barrier -> FMA} latency now hides under the other
// 3 resident blocks' compute. Per-output accumulation order (kc->kk), H
// formula, merge and epilogue arithmetic character-identical -> same rounding.
// Per thread: 1 gather set/chunk (was 2), acc[8][4] (was [8][8]).
// LDS ~17 KB; FCORE maps 64 rows x 128 cols as tr=tid&7 (8 rows), tc=tid>>3
// (4 cols). Bank check: sA writes 2-way (free), reads <=2-way, sW broadcast.
// ---------------------------------------------------------------------------
__global__ __launch_bounds__(256) void fused_tail_kernel(const float4* __restrict__ part_d,
                                                         const ushort4* __restrict__ part_i,
                                                         const float* __restrict__ G,
                                                         const float* __restrict__ x,
                                                         const float* __restrict__ w1,
                                                         const float* __restrict__ b1,
                                                         const float* __restrict__ w2,
                                                         const float* __restrict__ b2,
                                                         float* __restrict__ out) {
    __shared__ float  sA[16][68];     // H chunk [k][row]   4.25 KB
    __shared__ float  sW[16][132];    // w2 chunk [k][out]  8.25 KB
    __shared__ int4   sIdx[QBLK];     // merged top-3 per query
    __shared__ float4 sX[QBLK];       // query coords
    __shared__ float4 sWX[128];       // (wx0,wx1,wx2,b1) per channel
    const int row0 = blockIdx.x * QBLK;
    const int tid  = threadIdx.x;
    const int tr   = tid & 7;         // row-group: rows tr*8 .. tr*8+7
    const int tc   = tid >> 3;        // col-group: cols tc*4 .. tc*4+3
    const int b    = row0 >> 15;

    // ---- Phase 0: merge (threads 0-63) || stage w1-xyz table (64-191) ----
    if (tid < QBLK) {
        const int q = row0 + tid;
        float b0 = 1e30f, b1v = 1e30f, b2v = 1e30f;
        int   i0 = 0,     i1 = 0,      i2 = 0;
        #pragma unroll
        for (int s = 0; s < NSPLIT; ++s) {
            float4  d = part_d[(size_t)s * NQ + q];
            ushort4 u = part_i[(size_t)s * NQ + q];
            const int ux = u.x, uy = u.y, uz = u.z;
            if (d.x < b2v) { if (d.x < b1v) { b2v=b1v; i2=i1;
                if (d.x < b0) { b1v=b0; i1=i0; b0=d.x; i0=ux; }
                else          { b1v=d.x; i1=ux; } } else { b2v=d.x; i2=ux; } }
            if (d.y < b2v) { if (d.y < b1v) { b2v=b1v; i2=i1;
                if (d.y < b0) { b1v=b0; i1=i0; b0=d.y; i0=uy; }
                else          { b1v=d.y; i1=uy; } } else { b2v=d.y; i2=uy; } }
            if (d.z < b2v) { if (d.z < b1v) { b2v=b1v; i2=i1;
                if (d.z < b0) { b1v=b0; i1=i0; b0=d.z; i0=uz; }
                else          { b1v=d.z; i1=uz; } } else { b2v=d.z; i2=uz; } }
        }
        sIdx[tid] = make_int4(i0, i1, i2, 0);
        const float* xp = x + (size_t)q * 3;
        sX[tid] = make_float4(xp[0], xp[1], xp[2], 0.f);
    } else if (tid < QBLK + 128) {
        const int c = tid - QBLK;
        sWX[c] = make_float4(w1[(size_t)c*IN_+0], w1[(size_t)c*IN_+1],
                             w1[(size_t)c*IN_+2], b1[c]);
    }
    __syncthreads();

    // ---- kc loop: build H chunk in LDS + stage w2 chunk, then FMA core ----
    const float4* gb = (const float4*)G + (size_t)b * M_ * 32;
    float acc[8][4] = {};
    for (int kc = 0; kc < 8; ++kc) {
        {   // H build: one (row, kq) slot per thread (row = tid>>2 in [0,64))
            const int row = tid >> 2, kq = tid & 3;
            const int c4 = kc * 4 + kq;          // channel-group [0,32)
            int4 v = sIdx[row];
            float4 a = gb[(size_t)v.x * 32 + c4];
            float4 e = gb[(size_t)v.y * 32 + c4];
            float4 f = gb[(size_t)v.z * 32 + c4];
            float4 xr = sX[row];
            float4 w0  = sWX[c4*4+0], w1v = sWX[c4*4+1];
            float4 w2v = sWX[c4*4+2], w3  = sWX[c4*4+3];
            float h;
            h = ((a.x + e.x) + f.x) * (1.0f/3.0f);
            h = fmaf(w0.x,xr.x, fmaf(w0.y,xr.y, fmaf(w0.z,xr.z, h))) + w0.w;
            sA[kq*4+0][row] = h > 0.0f ? h : 0.0f;
            h = ((a.y + e.y) + f.y) * (1.0f/3.0f);
            h = fmaf(w1v.x,xr.x, fmaf(w1v.y,xr.y, fmaf(w1v.z,xr.z, h))) + w1v.w;
            sA[kq*4+1][row] = h > 0.0f ? h : 0.0f;
            h = ((a.z + e.z) + f.z) * (1.0f/3.0f);
            h = fmaf(w2v.x,xr.x, fmaf(w2v.y,xr.y, fmaf(w2v.z,xr.z, h))) + w2v.w;
            sA[kq*4+2][row] = h > 0.0f ? h : 0.0f;
            h = ((a.w + e.w) + f.w) * (1.0f/3.0f);
            h = fmaf(w3.x,xr.x, fmaf(w3.y,xr.y, fmaf(w3.z,xr.z, h))) + w3.w;
            sA[kq*4+3][row] = h > 0.0f ? h : 0.0f;
        }
        #pragma unroll
        for (int j = 0; j < 2; ++j) {   // w2 chunk: 128 outs x 4 kq slots
            int id = j * 256 + tid;
            int o  = id >> 2, kq = id & 3;
            float4 hh = ((const float4*)w2)[(size_t)o * 32 + kc * 4 + kq];
            sW[kq*4+0][o] = hh.x; sW[kq*4+1][o] = hh.y;
            sW[kq*4+2][o] = hh.z; sW[kq*4+3][o] = hh.w;
        }
        __syncthreads();
        #pragma unroll
        for (int kk = 0; kk < 16; ++kk) {
            float4 a0 = *(const float4*)&sA[kk][tr*8];
            float4 a1 = *(const float4*)&sA[kk][tr*8+4];
            float4 c0 = *(const float4*)&sW[kk][tc*4];
            float av[8] = {a0.x,a0.y,a0.z,a0.w,a1.x,a1.y,a1.z,a1.w};
            float bv[4] = {c0.x,c0.y,c0.z,c0.w};
            #pragma unroll
            for (int i = 0; i < 8; ++i)
                #pragma unroll
                for (int j = 0; j < 4; ++j)
                    acc[i][j] = fmaf(av[i], bv[j], acc[i][j]);
        }
        __syncthreads();
    }

    // ---- epilogue: bias + transposed store out[b][o][n] ----
    const int n0 = (row0 & (N_-1)) + tr*8;
    #pragma unroll
    for (int j = 0; j < 4; ++j) {
        int o = tc*4 + j;
        float bias = b2[o];
        float4 o0 = make_float4(acc[0][j]+bias, acc[1][j]+bias,
                                acc[2][j]+bias, acc[3][j]+bias);
        float4 o1 = make_float4(acc[4][j]+bias, acc[5][j]+bias,
                                acc[6][j]+bias, acc[7][j]+bias);
        float* dst = out + (((size_t)(b*OUT_ + o)) << 15) + n0;
        *(float4*)dst       = o0;
        *(float4*)(dst + 4) = o1;
    }
}

extern "C" void kernel_launch(void* const* d_in, const int* in_sizes, int n_in,
                              void* d_out, int out_size, void* d_ws, size_t ws_size,
                              hipStream_t stream) {
    const float* x        = (const float*)d_in[0];   // [B,N,3]
    const float* sx       = (const float*)d_in[1];   // [B,M,3]
    const float* features = (const float*)d_in[2];   // [B,M,C]
    const float* w1       = (const float*)d_in[3];   // [128,131]
    const float* b1       = (const float*)d_in[4];   // [128]
    const float* w2       = (const float*)d_in[5];   // [128,128]
    const float* b2       = (const float*)d_in[6];   // [128]
    float* out = (float*)d_out;                      // [B,128,N]

    char* ws = (char*)d_ws;
    // Layout:
    //   [2,6MB)     G        (4 MB)
    //   [33,49MB)   part_d   (16 MB)
    //   [49,57MB)   part_i   (8 MB, ushort4)
    float*   G      = (float*)  (ws + (2u  << 20));
    float4*  part_d = (float4*) (ws + (33u << 20));
    ushort4* part_i = (ushort4*)(ws + (33u << 20) + (16u<<20));

    fused_front_kernel<<<dim3(NNBLK + PREBLK), dim3(256), 0, stream>>>(x, sx, part_d, part_i,
                                                                      features, w1, G);
    fused_tail_kernel <<<dim3(NQ/QBLK), dim3(256), 0, stream>>>(part_d, part_i, G, x,
                                                                w1, b1, w2, b2, out);
}